// Round 1
// baseline (453.862 us; speedup 1.0000x reference)
//
#include <hip/hip_runtime.h>
#include <stdint.h>

// MultiBoxLoss: B=16, P=43008, G=128 (computed at runtime from in_sizes).
// Pipeline:
//  k_iou     : per (b,p) best_truth max/argmax over g; per (b,g) best_prior via
//              packed (iou_bits<<32)|~p atomicMax (exact first-occurrence ties).
//  k_scatter : numpy-semantics scatter of forced matches (gather olds first,
//              sequential writes so duplicate indices -> last wins).
//  k_main    : conf/pos, encode + smooth_l1 (loc & landm), CE via logsumexp,
//              mine[] array, level-1 histogram of mine float bits, double atomics.
//  k_sel1/k_h2/k_sel2/k_h3/k_sel3 : 3-stage radix select of k-th largest mine
//              per row (k = min(7*num_pos, P-1)); tie contribution added exactly.
//  k_fsum    : sum of mine strictly above threshold value.
//  k_fin     : normalize, write 3 outputs.

__device__ __forceinline__ float sl1(float x) {
  float a = fabsf(x);
  return a < 1.f ? 0.5f * a * a : a - 0.5f;
}

__device__ __forceinline__ double dwave(double v) {
#pragma unroll
  for (int o = 32; o; o >>= 1) v += __shfl_down(v, o);
  return v;
}

__global__ __launch_bounds__(256) void k_iou(
    const float* __restrict__ priors, const float* __restrict__ targets,
    float* __restrict__ bto, int* __restrict__ bti,
    unsigned long long* __restrict__ bp, int P, int G, int PT) {
  int b = blockIdx.x / PT, tile = blockIdx.x % PT;
  int tid = threadIdx.x;
  int p = tile * 256 + tid;
  int pl = p < P ? p : P - 1;

  __shared__ float tx1[128], ty1[128], tx2[128], ty2[128], ta[128];
  __shared__ unsigned long long sred[128 * 4];

  for (int g = tid; g < G; g += 256) {
    const float* t = targets + ((size_t)b * G + g) * 15;
    float x1 = t[0], y1 = t[1], x2 = t[2], y2 = t[3];
    tx1[g] = x1; ty1[g] = y1; tx2[g] = x2; ty2[g] = y2;
    ta[g] = (x2 - x1) * (y2 - y1);
  }
  __syncthreads();

  float4 pr = ((const float4*)priors)[pl];  // cx, cy, w, h
  float px1 = pr.x - pr.z * 0.5f, py1 = pr.y - pr.w * 0.5f;
  float px2 = pr.x + pr.z * 0.5f, py2 = pr.y + pr.w * 0.5f;
  float pa = (px2 - px1) * (py2 - py1);

  float best = -1.f;
  int bidx = 0;
  int lane = tid & 63, wid = tid >> 6;

  for (int g = 0; g < G; ++g) {
    float ltx = fmaxf(tx1[g], px1), lty = fmaxf(ty1[g], py1);
    float rbx = fminf(tx2[g], px2), rby = fminf(ty2[g], py2);
    float iw = fmaxf(rbx - ltx, 0.f), ih = fmaxf(rby - lty, 0.f);
    float inter = iw * ih;
    float iou = inter / (ta[g] + pa - inter);
    if (iou > best) { best = iou; bidx = g; }
    // wave allreduce max + first-lane-of-max -> per-wave best prior for g
    float v = iou;
#pragma unroll
    for (int o = 32; o; o >>= 1) v = fmaxf(v, __shfl_xor(v, o));
    unsigned long long msk = __ballot(iou == v);
    if (lane == 0) {
      int l = __ffsll((unsigned long long)msk) - 1;
      unsigned pp = (unsigned)(tile * 256 + wid * 64 + l);
      sred[g * 4 + wid] =
          ((unsigned long long)__float_as_uint(v) << 32) | (unsigned)(~pp);
    }
  }
  if (p < P) {
    bto[(size_t)b * P + p] = best;
    bti[(size_t)b * P + p] = bidx;
  }
  __syncthreads();
  for (int g = tid; g < G; g += 256) {
    unsigned long long m = sred[g * 4];
    unsigned long long m1 = sred[g * 4 + 1];
    unsigned long long m2 = sred[g * 4 + 2];
    unsigned long long m3 = sred[g * 4 + 3];
    if (m1 > m) m = m1;
    if (m2 > m) m = m2;
    if (m3 > m) m = m3;
    atomicMax(&bp[(size_t)b * G + g], m);
  }
}

__global__ void k_scatter(const unsigned long long* __restrict__ bp,
                          float* __restrict__ bto, int* __restrict__ bti,
                          int* __restrict__ anyv, int B, int P, int G) {
  extern __shared__ float olds[];
  int b = threadIdx.x;
  if (b >= B) return;
  float* o = olds + b * G;
  int av = 0;
  for (int g = 0; g < G; ++g) {
    unsigned long long m = bp[(size_t)b * G + g];
    unsigned pp = ~(unsigned)m;
    o[g] = bto[(size_t)b * P + pp];  // gather BEFORE any write (pre-scatter vals)
    float val = __uint_as_float((unsigned)(m >> 32));
    if (val >= 0.2f) av = 1;
  }
  for (int g = 0; g < G; ++g) {  // ascending order: duplicate idx -> last wins
    unsigned long long m = bp[(size_t)b * G + g];
    unsigned pp = ~(unsigned)m;
    float val = __uint_as_float((unsigned)(m >> 32));
    bto[(size_t)b * P + pp] = (val >= 0.2f) ? 2.0f : o[g];
    bti[(size_t)b * P + pp] = g;
  }
  anyv[b] = av;
}

__global__ __launch_bounds__(256) void k_main(
    const float* __restrict__ loc, const float* __restrict__ conf,
    const float* __restrict__ lm, const float* __restrict__ priors,
    const float* __restrict__ targets, const float* __restrict__ bto,
    const int* __restrict__ bti, const int* __restrict__ anyv,
    float* __restrict__ mine, unsigned* __restrict__ h1,
    int* __restrict__ num_pos, int* __restrict__ npt, double* __restrict__ acc,
    int P, int G, int PT) {
  int b = blockIdx.x / PT, tile = blockIdx.x % PT;
  int tid = threadIdx.x;
  int p = tile * 256 + tid;

  __shared__ float st[128 * 15];
  __shared__ unsigned hist[1024];
  __shared__ double rs[12];
  __shared__ int ri[4];

  for (int i = tid; i < G * 15; i += 256) st[i] = targets[(size_t)b * G * 15 + i];
  for (int i = tid; i < 1024; i += 256) hist[i] = 0;
  __syncthreads();

  double ll = 0, llm = 0, lc = 0;
  int np = 0;
  if (p < P) {
    size_t idx = (size_t)b * P + p;
    int av = anyv[b];
    float ov = bto[idx];
    int ti = bti[idx];
    bool pos = av && (ov >= 0.35f);

    float2 c = ((const float2*)conf)[idx];
    float mx = fmaxf(c.x, c.y);
    float lse = mx + logf(expf(c.x - mx) + expf(c.y - mx));
    float ce = lse - (pos ? c.y : c.x);
    float mv = pos ? 0.f : ce;
    mine[idx] = mv;
    atomicAdd(&hist[__float_as_uint(mv) >> 21], 1u);

    if (pos) {
      np = 1;
      lc = (double)ce;
      float4 pr = ((const float4*)priors)[p];
      const float* t = st + ti * 15;
      float dx = 0.1f * pr.z, dy = 0.1f * pr.w;
      float gx = ((t[0] + t[2]) * 0.5f - pr.x) / dx;
      float gy = ((t[1] + t[3]) * 0.5f - pr.y) / dy;
      float gw = logf((t[2] - t[0]) / pr.z) * 5.0f;  // /0.2
      float gh = logf((t[3] - t[1]) / pr.w) * 5.0f;
      float4 ld = ((const float4*)loc)[idx];
      ll = (double)(sl1(ld.x - gx) + sl1(ld.y - gy) + sl1(ld.z - gw) +
                    sl1(ld.w - gh));
      const float2* lmd = (const float2*)lm + idx * 5;
      float s = 0.f;
#pragma unroll
      for (int j = 0; j < 5; ++j) {
        float2 lv = lmd[j];
        float ex = (t[4 + 2 * j] - pr.x) / dx;
        float ey = (t[5 + 2 * j] - pr.y) / dy;
        s += sl1(lv.x - ex) + sl1(lv.y - ey);
      }
      llm = (double)s;
    }
  }

  ll = dwave(ll);
  llm = dwave(llm);
  lc = dwave(lc);
#pragma unroll
  for (int o = 32; o; o >>= 1) np += __shfl_down(np, o);
  int lane = tid & 63, wid = tid >> 6;
  if (lane == 0) { rs[wid] = ll; rs[4 + wid] = llm; rs[8 + wid] = lc; ri[wid] = np; }
  __syncthreads();  // also fences the shared-hist atomicAdds
  if (tid == 0) {
    double a = rs[0] + rs[1] + rs[2] + rs[3];
    double cL = rs[4] + rs[5] + rs[6] + rs[7];
    double d = rs[8] + rs[9] + rs[10] + rs[11];
    int n = ri[0] + ri[1] + ri[2] + ri[3];
    if (a != 0.0) atomicAdd(&acc[0], a);
    if (cL != 0.0) atomicAdd(&acc[1], cL);
    if (d != 0.0) atomicAdd(&acc[2], d);
    if (n) { atomicAdd(&num_pos[b], n); atomicAdd(npt, n); }
  }
  for (int i = tid; i < 1024; i += 256)
    if (hist[i]) atomicAdd(&h1[(size_t)b * 1024 + i], hist[i]);
}

__global__ void k_sel1(const unsigned* __restrict__ h1,
                       const int* __restrict__ num_pos, int P,
                       int* __restrict__ pfx1, int* __restrict__ k1) {
  int b = blockIdx.x, tid = threadIdx.x;
  const unsigned* h = h1 + (size_t)b * 1024;
  __shared__ unsigned part[256];
  part[tid] = h[tid * 4] + h[tid * 4 + 1] + h[tid * 4 + 2] + h[tid * 4 + 3];
  __syncthreads();
  if (tid == 0) {
    long long k = 7LL * (long long)num_pos[b];
    long long cap = P - 1;
    if (k > cap) k = cap;
    if (k <= 0) { pfx1[b] = -1; k1[b] = 0; }
    else {
      long long cum = 0;
      int seg = 0;
      for (int t = 255; t >= 0; --t) {
        if (cum + part[t] >= k) { seg = t; break; }
        cum += part[t];
      }
      int bin = seg * 4;
      for (int j = 3; j >= 0; --j) {
        unsigned hv = h[seg * 4 + j];
        if (cum + hv >= k) { bin = seg * 4 + j; break; }
        cum += hv;
      }
      pfx1[b] = bin;
      k1[b] = (int)(k - cum);
    }
  }
}

__global__ __launch_bounds__(256) void k_h2(const float* __restrict__ mine,
                                            const int* __restrict__ pfx1,
                                            unsigned* __restrict__ h2, int P,
                                            int PT) {
  int b = blockIdx.x / PT;
  int p = (blockIdx.x % PT) * 256 + threadIdx.x;
  __shared__ unsigned hist[2048];
  for (int i = threadIdx.x; i < 2048; i += 256) hist[i] = 0;
  __syncthreads();
  int pf = pfx1[b];
  if (p < P) {
    unsigned bits = __float_as_uint(mine[(size_t)b * P + p]);
    if ((int)(bits >> 21) == pf) atomicAdd(&hist[(bits >> 10) & 2047], 1u);
  }
  __syncthreads();
  for (int i = threadIdx.x; i < 2048; i += 256)
    if (hist[i]) atomicAdd(&h2[(size_t)b * 2048 + i], hist[i]);
}

__global__ void k_sel2(const unsigned* __restrict__ h2,
                       const int* __restrict__ pfx1, const int* __restrict__ k1,
                       int* __restrict__ pfx21, int* __restrict__ k2) {
  int b = blockIdx.x, tid = threadIdx.x;
  const unsigned* h = h2 + (size_t)b * 2048;
  __shared__ unsigned part[256];
  unsigned s = 0;
#pragma unroll
  for (int j = 0; j < 8; ++j) s += h[tid * 8 + j];
  part[tid] = s;
  __syncthreads();
  if (tid == 0) {
    int pf = pfx1[b];
    if (pf < 0) { pfx21[b] = -1; k2[b] = 0; }
    else {
      long long k = k1[b];
      long long cum = 0;
      int seg = 0;
      for (int t = 255; t >= 0; --t) {
        if (cum + part[t] >= k) { seg = t; break; }
        cum += part[t];
      }
      int bin = seg * 8;
      for (int j = 7; j >= 0; --j) {
        unsigned hv = h[seg * 8 + j];
        if (cum + hv >= k) { bin = seg * 8 + j; break; }
        cum += hv;
      }
      pfx21[b] = (pf << 11) | bin;
      k2[b] = (int)(k - cum);
    }
  }
}

__global__ __launch_bounds__(256) void k_h3(const float* __restrict__ mine,
                                            const int* __restrict__ pfx21,
                                            unsigned* __restrict__ h3, int P,
                                            int PT) {
  int b = blockIdx.x / PT;
  int p = (blockIdx.x % PT) * 256 + threadIdx.x;
  __shared__ unsigned hist[1024];
  for (int i = threadIdx.x; i < 1024; i += 256) hist[i] = 0;
  __syncthreads();
  int pf = pfx21[b];
  if (p < P) {
    unsigned bits = __float_as_uint(mine[(size_t)b * P + p]);
    if ((int)(bits >> 10) == pf) atomicAdd(&hist[bits & 1023], 1u);
  }
  __syncthreads();
  for (int i = threadIdx.x; i < 1024; i += 256)
    if (hist[i]) atomicAdd(&h3[(size_t)b * 1024 + i], hist[i]);
}

__global__ void k_sel3(const unsigned* __restrict__ h3,
                       const int* __restrict__ pfx21, const int* __restrict__ k2,
                       int* __restrict__ tbits, double* __restrict__ acc) {
  int b = blockIdx.x, tid = threadIdx.x;
  const unsigned* h = h3 + (size_t)b * 1024;
  __shared__ unsigned part[256];
  part[tid] = h[tid * 4] + h[tid * 4 + 1] + h[tid * 4 + 2] + h[tid * 4 + 3];
  __syncthreads();
  if (tid == 0) {
    int pf = pfx21[b];
    if (pf < 0) { tbits[b] = -1; }  // 0xFFFFFFFF: nothing selected
    else {
      long long k = k2[b];
      long long cum = 0;
      int seg = 0;
      for (int t = 255; t >= 0; --t) {
        if (cum + part[t] >= k) { seg = t; break; }
        cum += part[t];
      }
      int bin = seg * 4;
      for (int j = 3; j >= 0; --j) {
        unsigned hv = h[seg * 4 + j];
        if (cum + hv >= k) { bin = seg * 4 + j; break; }
        cum += hv;
      }
      unsigned tb = ((unsigned)pf << 10) | (unsigned)bin;
      tbits[b] = (int)tb;
      long long nat = k - cum;  // # elements at exactly value t to include
      double add = (double)nat * (double)__uint_as_float(tb);
      if (add != 0.0) atomicAdd(&acc[2], add);
    }
  }
}

__global__ __launch_bounds__(256) void k_fsum(const float* __restrict__ mine,
                                              const int* __restrict__ tbits,
                                              double* __restrict__ acc, int P,
                                              int PT) {
  int b = blockIdx.x / PT;
  int p = (blockIdx.x % PT) * 256 + threadIdx.x;
  unsigned tb = (unsigned)tbits[b];
  double v = 0.0;
  if (p < P) {
    unsigned bits = __float_as_uint(mine[(size_t)b * P + p]);
    if (bits > tb) v = (double)__uint_as_float(bits);
  }
  v = dwave(v);
  __shared__ double rs[4];
  int lane = threadIdx.x & 63, wid = threadIdx.x >> 6;
  if (lane == 0) rs[wid] = v;
  __syncthreads();
  if (threadIdx.x == 0) {
    double t = rs[0] + rs[1] + rs[2] + rs[3];
    if (t != 0.0) atomicAdd(&acc[2], t);
  }
}

__global__ void k_fin(const double* __restrict__ acc, const int* __restrict__ npt,
                      float* __restrict__ out) {
  float Nf = (float)npt[0];
  if (Nf < 1.f) Nf = 1.f;
  double N = (double)Nf;
  out[0] = (float)(acc[0] / N);  // loss_l / N
  out[1] = (float)(acc[2] / N);  // loss_c / N
  out[2] = (float)(acc[1] / N);  // loss_landm / N1  (N1 == N)
}

extern "C" void kernel_launch(void* const* d_in, const int* in_sizes, int n_in,
                              void* d_out, int out_size, void* d_ws,
                              size_t ws_size, hipStream_t stream) {
  const float* loc = (const float*)d_in[0];
  const float* conf = (const float*)d_in[1];
  const float* lm = (const float*)d_in[2];
  const float* priors = (const float*)d_in[3];
  const float* targets = (const float*)d_in[4];

  int P = in_sizes[3] / 4;
  int B = in_sizes[0] / (4 * P);
  int G = in_sizes[4] / (15 * B);
  int PT = (P + 255) / 256;

  char* w = (char*)d_ws;
  size_t off = 0;
  unsigned long long* bp = (unsigned long long*)(w + off);
  off += (size_t)B * G * 8;
  int* ctrl = (int*)(w + off);
  off += (size_t)(8 * B + 8) * 4;
  int* anyv = ctrl;
  int* num_pos = ctrl + B;
  int* pfx1 = ctrl + 2 * B;
  int* k1 = ctrl + 3 * B;
  int* pfx21 = ctrl + 4 * B;
  int* k2 = ctrl + 5 * B;
  int* tbits = ctrl + 6 * B;
  int* npt = ctrl + 7 * B;
  off = (off + 7) & ~(size_t)7;
  double* acc = (double*)(w + off);
  off += 3 * 8;
  unsigned* h1 = (unsigned*)(w + off);
  off += (size_t)B * 1024 * 4;
  unsigned* h2 = (unsigned*)(w + off);
  off += (size_t)B * 2048 * 4;
  unsigned* h3 = (unsigned*)(w + off);
  off += (size_t)B * 1024 * 4;
  size_t clear_bytes = off;
  off = (off + 255) & ~(size_t)255;
  float* bto = (float*)(w + off);
  off += (size_t)B * P * 4;
  int* bti = (int*)(w + off);
  off += (size_t)B * P * 4;
  float* mine = (float*)(w + off);
  off += (size_t)B * P * 4;

  hipMemsetAsync(d_ws, 0, clear_bytes, stream);

  k_iou<<<B * PT, 256, 0, stream>>>(priors, targets, bto, bti, bp, P, G, PT);
  k_scatter<<<1, B, (size_t)B * G * 4, stream>>>(bp, bto, bti, anyv, B, P, G);
  k_main<<<B * PT, 256, 0, stream>>>(loc, conf, lm, priors, targets, bto, bti,
                                     anyv, mine, h1, num_pos, npt, acc, P, G, PT);
  k_sel1<<<B, 256, 0, stream>>>(h1, num_pos, P, pfx1, k1);
  k_h2<<<B * PT, 256, 0, stream>>>(mine, pfx1, h2, P, PT);
  k_sel2<<<B, 256, 0, stream>>>(h2, pfx1, k1, pfx21, k2);
  k_h3<<<B * PT, 256, 0, stream>>>(mine, pfx21, h3, P, PT);
  k_sel3<<<B, 256, 0, stream>>>(h3, pfx21, k2, tbits, acc);
  k_fsum<<<B * PT, 256, 0, stream>>>(mine, tbits, acc, P, PT);
  k_fin<<<1, 1, 0, stream>>>(acc, npt, (float*)d_out);
}

// Round 2
// 340.842 us; speedup vs baseline: 1.3316x; 1.3316x over previous
//
#include <hip/hip_runtime.h>
#include <stdint.h>

// MultiBoxLoss B=16, P=43008, G=128.
// R2: k_iou keeps only per-thread best-truth (div-free cross-mult compare, one
//     IEEE div per thread at end). New k_bp does best-prior: 8 GTs/block in
//     registers, block-reduce over a P-chunk, global atomicMax on packed
//     (iou_bits<<32)|~p. k_scatter parallelized (B blocks x G threads,
//     last-dup-wins via shared pp table). k_sel* use parallel suffix scan.

#define GC 8  // GTs per k_bp block

__device__ __forceinline__ float sl1(float x) {
  float a = fabsf(x);
  return a < 1.f ? 0.5f * a * a : a - 0.5f;
}

__device__ __forceinline__ double dwave(double v) {
#pragma unroll
  for (int o = 32; o; o >>= 1) v += __shfl_down(v, o);
  return v;
}

// candidate (ni,nu,np_) beats (ci,cu,cp)?  (invalid marked ci<0)
__device__ __forceinline__ void combine(float& ci, float& cu, unsigned& cp,
                                        float ni, float nu, unsigned np_) {
  if (ni < 0.f) return;
  bool take;
  if (ci < 0.f) take = true;
  else {
    float a = ni * cu, bq = ci * nu;
    take = (a > bq) || (a == bq && np_ < cp);
  }
  if (take) { ci = ni; cu = nu; cp = np_; }
}

__global__ __launch_bounds__(256) void k_iou(
    const float* __restrict__ priors, const float* __restrict__ targets,
    float* __restrict__ bto, int* __restrict__ bti, int P, int G, int PT) {
  int b = blockIdx.x / PT, tile = blockIdx.x % PT;
  int tid = threadIdx.x;
  int p = tile * 256 + tid;
  int pl = p < P ? p : P - 1;

  __shared__ float tx1[128], ty1[128], tx2[128], ty2[128], ta[128];
  for (int g = tid; g < G; g += 256) {
    const float* t = targets + ((size_t)b * G + g) * 15;
    float x1 = t[0], y1 = t[1], x2 = t[2], y2 = t[3];
    tx1[g] = x1; ty1[g] = y1; tx2[g] = x2; ty2[g] = y2;
    ta[g] = (x2 - x1) * (y2 - y1);
  }
  __syncthreads();

  float4 pr = ((const float4*)priors)[pl];
  float px1 = pr.x - pr.z * 0.5f, py1 = pr.y - pr.w * 0.5f;
  float px2 = pr.x + pr.z * 0.5f, py2 = pr.y + pr.w * 0.5f;
  float pa = (px2 - px1) * (py2 - py1);

  float bi = -1.f, bu = 1.f;
  int bidx = 0;
#pragma unroll 4
  for (int g = 0; g < G; ++g) {
    float ltx = fmaxf(tx1[g], px1), lty = fmaxf(ty1[g], py1);
    float rbx = fminf(tx2[g], px2), rby = fminf(ty2[g], py2);
    float iw = fmaxf(rbx - ltx, 0.f), ih = fmaxf(rby - lty, 0.f);
    float inter = iw * ih;
    float uni = ta[g] + pa - inter;
    if (inter * bu > bi * uni) { bi = inter; bu = uni; bidx = g; }
  }
  if (p < P) {
    bto[(size_t)b * P + p] = bi / bu;  // one IEEE div per thread
    bti[(size_t)b * P + p] = bidx;
  }
}

__global__ __launch_bounds__(256) void k_bp(
    const float* __restrict__ priors, const float* __restrict__ targets,
    unsigned long long* __restrict__ bp, int P, int G, int NGC, int PC) {
  int bc = blockIdx.x;
  int pc = bc % PC;
  int gcb = (bc / PC) % NGC;
  int b = bc / (PC * NGC);
  int g0 = gcb * GC;
  int tid = threadIdx.x;

  __shared__ float sg[GC * 5];
  if (tid < GC * 5) {
    int j = tid / 5, c = tid % 5;
    int g = g0 + j;
    float v = 0.f;
    if (g < G) {
      const float* t = targets + ((size_t)b * G + g) * 15;
      v = (c < 4) ? t[c] : (t[2] - t[0]) * (t[3] - t[1]);
    }
    sg[tid] = v;
  }
  __syncthreads();

  float gx1[GC], gy1[GC], gx2[GC], gy2[GC], ga[GC];
#pragma unroll
  for (int j = 0; j < GC; ++j) {
    gx1[j] = sg[j * 5 + 0]; gy1[j] = sg[j * 5 + 1];
    gx2[j] = sg[j * 5 + 2]; gy2[j] = sg[j * 5 + 3];
    ga[j] = sg[j * 5 + 4];
  }

  float bi[GC], bu[GC];
  unsigned bpp[GC];
#pragma unroll
  for (int j = 0; j < GC; ++j) { bi[j] = -1.f; bu[j] = 1.f; bpp[j] = 0; }

  int chunk = (P + PC - 1) / PC;
  int ps = pc * chunk;
  int pe = ps + chunk; if (pe > P) pe = P;

  for (int p = ps + tid; p < pe; p += 256) {
    float4 pr = ((const float4*)priors)[p];
    float px1 = pr.x - pr.z * 0.5f, py1 = pr.y - pr.w * 0.5f;
    float px2 = pr.x + pr.z * 0.5f, py2 = pr.y + pr.w * 0.5f;
    float pa = (px2 - px1) * (py2 - py1);
#pragma unroll
    for (int j = 0; j < GC; ++j) {
      float ltx = fmaxf(gx1[j], px1), lty = fmaxf(gy1[j], py1);
      float rbx = fminf(gx2[j], px2), rby = fminf(gy2[j], py2);
      float iw = fmaxf(rbx - ltx, 0.f), ih = fmaxf(rby - lty, 0.f);
      float inter = iw * ih;
      float uni = ga[j] + pa - inter;
      if (inter * bu[j] > bi[j] * uni) { bi[j] = inter; bu[j] = uni; bpp[j] = (unsigned)p; }
    }
  }

  __shared__ float si[GC * 256], su[GC * 256];
  __shared__ unsigned sp[GC * 256];
#pragma unroll
  for (int j = 0; j < GC; ++j) {
    si[j * 256 + tid] = bi[j]; su[j * 256 + tid] = bu[j]; sp[j * 256 + tid] = bpp[j];
  }
  __syncthreads();
  // level 1: thread tid -> (j = tid>>5, s = tid&31): combine 8 entries
  {
    int j = tid >> 5, s = tid & 31;
    float ci = -1.f, cu = 1.f; unsigned cp = 0;
    for (int t = s; t < 256; t += 32)
      combine(ci, cu, cp, si[j * 256 + t], su[j * 256 + t], sp[j * 256 + t]);
    __syncthreads();
    si[j * 256 + s] = ci; su[j * 256 + s] = cu; sp[j * 256 + s] = cp;
  }
  __syncthreads();
  if (tid < GC) {
    int j = tid;
    float ci = -1.f, cu = 1.f; unsigned cp = 0;
    for (int t = 0; t < 32; ++t)
      combine(ci, cu, cp, si[j * 256 + t], su[j * 256 + t], sp[j * 256 + t]);
    int g = g0 + j;
    if (g < G && ci >= 0.f) {
      float v = ci / cu;
      unsigned long long packed =
          ((unsigned long long)__float_as_uint(v) << 32) | (unsigned)(~cp);
      atomicMax(&bp[(size_t)b * G + g], packed);
    }
  }
}

__global__ void k_scatter(const unsigned long long* __restrict__ bp,
                          float* __restrict__ bto, int* __restrict__ bti,
                          int* __restrict__ anyv, int P, int G) {
  int b = blockIdx.x, g = threadIdx.x;
  __shared__ unsigned spp[128];
  __shared__ int s_any;
  if (g == 0) s_any = 0;
  __syncthreads();
  unsigned long long m = bp[(size_t)b * G + g];
  unsigned pp = ~(unsigned)m;
  float val = __uint_as_float((unsigned)(m >> 32));
  bool ok = (m != 0ULL);
  float oldv = 0.f;
  if (ok) oldv = bto[(size_t)b * P + pp];  // gather before any write
  spp[g] = ok ? pp : 0xFFFFFFFFu;
  if (ok && val >= 0.2f) s_any = 1;  // benign same-value race
  __syncthreads();
  bool win = ok;
  for (int g2 = g + 1; g2 < G; ++g2)
    if (spp[g2] == pp) win = false;  // last duplicate wins
  if (win) {
    bto[(size_t)b * P + pp] = (val >= 0.2f) ? 2.0f : oldv;
    bti[(size_t)b * P + pp] = g;
  }
  __syncthreads();
  if (g == 0) anyv[b] = s_any;
}

__global__ __launch_bounds__(256) void k_main(
    const float* __restrict__ loc, const float* __restrict__ conf,
    const float* __restrict__ lm, const float* __restrict__ priors,
    const float* __restrict__ targets, const float* __restrict__ bto,
    const int* __restrict__ bti, const int* __restrict__ anyv,
    float* __restrict__ mine, unsigned* __restrict__ h1,
    int* __restrict__ num_pos, int* __restrict__ npt, double* __restrict__ acc,
    int P, int G, int PT) {
  int b = blockIdx.x / PT, tile = blockIdx.x % PT;
  int tid = threadIdx.x;
  int p = tile * 256 + tid;

  __shared__ float st[128 * 15];
  __shared__ unsigned hist[1024];
  __shared__ double rs[12];
  __shared__ int ri[4];

  for (int i = tid; i < G * 15; i += 256) st[i] = targets[(size_t)b * G * 15 + i];
  for (int i = tid; i < 1024; i += 256) hist[i] = 0;
  __syncthreads();

  double ll = 0, llm = 0, lc = 0;
  int np = 0;
  if (p < P) {
    size_t idx = (size_t)b * P + p;
    int av = anyv[b];
    float ov = bto[idx];
    int ti = bti[idx];
    bool pos = av && (ov >= 0.35f);

    float2 c = ((const float2*)conf)[idx];
    float mx = fmaxf(c.x, c.y);
    float lse = mx + logf(expf(c.x - mx) + expf(c.y - mx));
    float ce = lse - (pos ? c.y : c.x);
    float mv = pos ? 0.f : ce;
    mine[idx] = mv;
    atomicAdd(&hist[__float_as_uint(mv) >> 21], 1u);

    if (pos) {
      np = 1;
      lc = (double)ce;
      float4 pr = ((const float4*)priors)[p];
      const float* t = st + ti * 15;
      float dx = 0.1f * pr.z, dy = 0.1f * pr.w;
      float gx = ((t[0] + t[2]) * 0.5f - pr.x) / dx;
      float gy = ((t[1] + t[3]) * 0.5f - pr.y) / dy;
      float gw = logf((t[2] - t[0]) / pr.z) * 5.0f;
      float gh = logf((t[3] - t[1]) / pr.w) * 5.0f;
      float4 ld = ((const float4*)loc)[idx];
      ll = (double)(sl1(ld.x - gx) + sl1(ld.y - gy) + sl1(ld.z - gw) +
                    sl1(ld.w - gh));
      const float2* lmd = (const float2*)lm + idx * 5;
      float s = 0.f;
#pragma unroll
      for (int j = 0; j < 5; ++j) {
        float2 lv = lmd[j];
        float ex = (t[4 + 2 * j] - pr.x) / dx;
        float ey = (t[5 + 2 * j] - pr.y) / dy;
        s += sl1(lv.x - ex) + sl1(lv.y - ey);
      }
      llm = (double)s;
    }
  }

  ll = dwave(ll);
  llm = dwave(llm);
  lc = dwave(lc);
#pragma unroll
  for (int o = 32; o; o >>= 1) np += __shfl_down(np, o);
  int lane = tid & 63, wid = tid >> 6;
  if (lane == 0) { rs[wid] = ll; rs[4 + wid] = llm; rs[8 + wid] = lc; ri[wid] = np; }
  __syncthreads();
  if (tid == 0) {
    double a = rs[0] + rs[1] + rs[2] + rs[3];
    double cL = rs[4] + rs[5] + rs[6] + rs[7];
    double d = rs[8] + rs[9] + rs[10] + rs[11];
    int n = ri[0] + ri[1] + ri[2] + ri[3];
    if (a != 0.0) atomicAdd(&acc[0], a);
    if (cL != 0.0) atomicAdd(&acc[1], cL);
    if (d != 0.0) atomicAdd(&acc[2], d);
    if (n) { atomicAdd(&num_pos[b], n); atomicAdd(npt, n); }
  }
  for (int i = tid; i < 1024; i += 256)
    if (hist[i]) atomicAdd(&h1[(size_t)b * 1024 + i], hist[i]);
}

// parallel suffix-scan select over 256 parts; sub-bin scan by owner thread
__global__ __launch_bounds__(256) void k_sel1(const unsigned* __restrict__ h1,
                                              const int* __restrict__ num_pos,
                                              int P, int* __restrict__ pfx1,
                                              int* __restrict__ k1) {
  int b = blockIdx.x, tid = threadIdx.x;
  const unsigned* h = h1 + (size_t)b * 1024;
  __shared__ unsigned S[256];
  unsigned p0 = h[tid * 4], p1 = h[tid * 4 + 1], p2 = h[tid * 4 + 2],
           p3 = h[tid * 4 + 3];
  S[tid] = p0 + p1 + p2 + p3;
  __syncthreads();
  for (int off = 1; off < 256; off <<= 1) {
    unsigned add = (tid + off < 256) ? S[tid + off] : 0;
    __syncthreads();
    S[tid] += add;
    __syncthreads();
  }
  long long k = 7LL * (long long)num_pos[b];
  long long cap = P - 1;
  if (k > cap) k = cap;
  int cnt = __syncthreads_count(k > 0 && (long long)S[tid] >= k);
  if (cnt == 0) {
    if (tid == 0) { pfx1[b] = -1; k1[b] = 0; }
    return;
  }
  int seg = cnt - 1;
  if (tid == seg) {
    long long cum = (seg + 1 < 256) ? (long long)S[seg + 1] : 0;
    unsigned hv[4] = {p0, p1, p2, p3};
    int bin = seg * 4;
    for (int j = 3; j >= 0; --j) {
      if (cum + hv[j] >= k) { bin = seg * 4 + j; break; }
      cum += hv[j];
    }
    pfx1[b] = bin;
    k1[b] = (int)(k - cum);
  }
}

__global__ __launch_bounds__(256) void k_h2(const float* __restrict__ mine,
                                            const int* __restrict__ pfx1,
                                            unsigned* __restrict__ h2, int P,
                                            int PT) {
  int b = blockIdx.x / PT;
  int p = (blockIdx.x % PT) * 256 + threadIdx.x;
  __shared__ unsigned hist[2048];
  for (int i = threadIdx.x; i < 2048; i += 256) hist[i] = 0;
  __syncthreads();
  int pf = pfx1[b];
  if (p < P) {
    unsigned bits = __float_as_uint(mine[(size_t)b * P + p]);
    if ((int)(bits >> 21) == pf) atomicAdd(&hist[(bits >> 10) & 2047], 1u);
  }
  __syncthreads();
  for (int i = threadIdx.x; i < 2048; i += 256)
    if (hist[i]) atomicAdd(&h2[(size_t)b * 2048 + i], hist[i]);
}

__global__ __launch_bounds__(256) void k_sel2(const unsigned* __restrict__ h2,
                                              const int* __restrict__ pfx1,
                                              const int* __restrict__ k1,
                                              int* __restrict__ pfx21,
                                              int* __restrict__ k2) {
  int b = blockIdx.x, tid = threadIdx.x;
  const unsigned* h = h2 + (size_t)b * 2048;
  __shared__ unsigned S[256];
  unsigned hv[8];
  unsigned s = 0;
#pragma unroll
  for (int j = 0; j < 8; ++j) { hv[j] = h[tid * 8 + j]; s += hv[j]; }
  S[tid] = s;
  __syncthreads();
  for (int off = 1; off < 256; off <<= 1) {
    unsigned add = (tid + off < 256) ? S[tid + off] : 0;
    __syncthreads();
    S[tid] += add;
    __syncthreads();
  }
  int pf = pfx1[b];
  long long k = (long long)k1[b];
  int cnt = __syncthreads_count(pf >= 0 && (long long)S[tid] >= k);
  if (cnt == 0) {
    if (tid == 0) { pfx21[b] = -1; k2[b] = 0; }
    return;
  }
  int seg = cnt - 1;
  if (tid == seg) {
    long long cum = (seg + 1 < 256) ? (long long)S[seg + 1] : 0;
    int bin = seg * 8;
    for (int j = 7; j >= 0; --j) {
      if (cum + hv[j] >= k) { bin = seg * 8 + j; break; }
      cum += hv[j];
    }
    pfx21[b] = (pf << 11) | bin;
    k2[b] = (int)(k - cum);
  }
}

__global__ __launch_bounds__(256) void k_h3(const float* __restrict__ mine,
                                            const int* __restrict__ pfx21,
                                            unsigned* __restrict__ h3, int P,
                                            int PT) {
  int b = blockIdx.x / PT;
  int p = (blockIdx.x % PT) * 256 + threadIdx.x;
  __shared__ unsigned hist[1024];
  for (int i = threadIdx.x; i < 1024; i += 256) hist[i] = 0;
  __syncthreads();
  int pf = pfx21[b];
  if (p < P) {
    unsigned bits = __float_as_uint(mine[(size_t)b * P + p]);
    if ((int)(bits >> 10) == pf) atomicAdd(&hist[bits & 1023], 1u);
  }
  __syncthreads();
  for (int i = threadIdx.x; i < 1024; i += 256)
    if (hist[i]) atomicAdd(&h3[(size_t)b * 1024 + i], hist[i]);
}

__global__ __launch_bounds__(256) void k_sel3(const unsigned* __restrict__ h3,
                                              const int* __restrict__ pfx21,
                                              const int* __restrict__ k2,
                                              int* __restrict__ tbits,
                                              double* __restrict__ acc) {
  int b = blockIdx.x, tid = threadIdx.x;
  const unsigned* h = h3 + (size_t)b * 1024;
  __shared__ unsigned S[256];
  unsigned p0 = h[tid * 4], p1 = h[tid * 4 + 1], p2 = h[tid * 4 + 2],
           p3 = h[tid * 4 + 3];
  S[tid] = p0 + p1 + p2 + p3;
  __syncthreads();
  for (int off = 1; off < 256; off <<= 1) {
    unsigned add = (tid + off < 256) ? S[tid + off] : 0;
    __syncthreads();
    S[tid] += add;
    __syncthreads();
  }
  int pf = pfx21[b];
  long long k = (long long)k2[b];
  int cnt = __syncthreads_count(pf >= 0 && (long long)S[tid] >= k);
  if (cnt == 0) {
    if (tid == 0) tbits[b] = -1;
    return;
  }
  int seg = cnt - 1;
  if (tid == seg) {
    long long cum = (seg + 1 < 256) ? (long long)S[seg + 1] : 0;
    unsigned hv[4] = {p0, p1, p2, p3};
    int bin = seg * 4;
    for (int j = 3; j >= 0; --j) {
      if (cum + hv[j] >= k) { bin = seg * 4 + j; break; }
      cum += hv[j];
    }
    unsigned tb = ((unsigned)pf << 10) | (unsigned)bin;
    tbits[b] = (int)tb;
    long long nat = k - cum;
    double add = (double)nat * (double)__uint_as_float(tb);
    if (add != 0.0) atomicAdd(&acc[2], add);
  }
}

__global__ __launch_bounds__(256) void k_fsum(const float* __restrict__ mine,
                                              const int* __restrict__ tbits,
                                              double* __restrict__ acc, int P,
                                              int PT) {
  int b = blockIdx.x / PT;
  int p = (blockIdx.x % PT) * 256 + threadIdx.x;
  unsigned tb = (unsigned)tbits[b];
  double v = 0.0;
  if (p < P) {
    unsigned bits = __float_as_uint(mine[(size_t)b * P + p]);
    if (bits > tb) v = (double)__uint_as_float(bits);
  }
  v = dwave(v);
  __shared__ double rs[4];
  int lane = threadIdx.x & 63, wid = threadIdx.x >> 6;
  if (lane == 0) rs[wid] = v;
  __syncthreads();
  if (threadIdx.x == 0) {
    double t = rs[0] + rs[1] + rs[2] + rs[3];
    if (t != 0.0) atomicAdd(&acc[2], t);
  }
}

__global__ void k_fin(const double* __restrict__ acc, const int* __restrict__ npt,
                      float* __restrict__ out) {
  float Nf = (float)npt[0];
  if (Nf < 1.f) Nf = 1.f;
  double N = (double)Nf;
  out[0] = (float)(acc[0] / N);
  out[1] = (float)(acc[2] / N);
  out[2] = (float)(acc[1] / N);
}

extern "C" void kernel_launch(void* const* d_in, const int* in_sizes, int n_in,
                              void* d_out, int out_size, void* d_ws,
                              size_t ws_size, hipStream_t stream) {
  const float* loc = (const float*)d_in[0];
  const float* conf = (const float*)d_in[1];
  const float* lm = (const float*)d_in[2];
  const float* priors = (const float*)d_in[3];
  const float* targets = (const float*)d_in[4];

  int P = in_sizes[3] / 4;
  int B = in_sizes[0] / (4 * P);
  int G = in_sizes[4] / (15 * B);
  int PT = (P + 255) / 256;
  int NGC = (G + GC - 1) / GC;
  int PC = 4;

  char* w = (char*)d_ws;
  size_t off = 0;
  unsigned long long* bp = (unsigned long long*)(w + off);
  off += (size_t)B * G * 8;
  int* ctrl = (int*)(w + off);
  off += (size_t)(8 * B + 8) * 4;
  int* anyv = ctrl;
  int* num_pos = ctrl + B;
  int* pfx1 = ctrl + 2 * B;
  int* k1 = ctrl + 3 * B;
  int* pfx21 = ctrl + 4 * B;
  int* k2 = ctrl + 5 * B;
  int* tbits = ctrl + 6 * B;
  int* npt = ctrl + 7 * B;
  off = (off + 7) & ~(size_t)7;
  double* acc = (double*)(w + off);
  off += 3 * 8;
  unsigned* h1 = (unsigned*)(w + off);
  off += (size_t)B * 1024 * 4;
  unsigned* h2 = (unsigned*)(w + off);
  off += (size_t)B * 2048 * 4;
  unsigned* h3 = (unsigned*)(w + off);
  off += (size_t)B * 1024 * 4;
  size_t clear_bytes = off;
  off = (off + 255) & ~(size_t)255;
  float* bto = (float*)(w + off);
  off += (size_t)B * P * 4;
  int* bti = (int*)(w + off);
  off += (size_t)B * P * 4;
  float* mine = (float*)(w + off);
  off += (size_t)B * P * 4;

  hipMemsetAsync(d_ws, 0, clear_bytes, stream);

  k_iou<<<B * PT, 256, 0, stream>>>(priors, targets, bto, bti, P, G, PT);
  k_bp<<<B * NGC * PC, 256, 0, stream>>>(priors, targets, bp, P, G, NGC, PC);
  k_scatter<<<B, G, 0, stream>>>(bp, bto, bti, anyv, P, G);
  k_main<<<B * PT, 256, 0, stream>>>(loc, conf, lm, priors, targets, bto, bti,
                                     anyv, mine, h1, num_pos, npt, acc, P, G, PT);
  k_sel1<<<B, 256, 0, stream>>>(h1, num_pos, P, pfx1, k1);
  k_h2<<<B * PT, 256, 0, stream>>>(mine, pfx1, h2, P, PT);
  k_sel2<<<B, 256, 0, stream>>>(h2, pfx1, k1, pfx21, k2);
  k_h3<<<B * PT, 256, 0, stream>>>(mine, pfx21, h3, P, PT);
  k_sel3<<<B, 256, 0, stream>>>(h3, pfx21, k2, tbits, acc);
  k_fsum<<<B * PT, 256, 0, stream>>>(mine, tbits, acc, P, PT);
  k_fin<<<1, 1, 0, stream>>>(acc, npt, (float*)d_out);
}

// Round 3
// 224.416 us; speedup vs baseline: 2.0224x; 1.5188x over previous
//
#include <hip/hip_runtime.h>
#include <stdint.h>

// MultiBoxLoss B=16, P=43008, G=128.
// R3: removed ALL global f64 atomicAdds (they compile to CAS loops and the
//     same-address contention serialized k_main/k_fsum, ~100us each).
//     Per-block partial sums -> ws arrays; k_fin (1x256) reduces them.
//     k_sel1 reduces per-block pos counts to num_pos[b].

#define GC 8  // GTs per k_bp block

__device__ __forceinline__ float sl1(float x) {
  float a = fabsf(x);
  return a < 1.f ? 0.5f * a * a : a - 0.5f;
}

__device__ __forceinline__ double dwave(double v) {
#pragma unroll
  for (int o = 32; o; o >>= 1) v += __shfl_down(v, o);
  return v;
}

__device__ __forceinline__ void combine(float& ci, float& cu, unsigned& cp,
                                        float ni, float nu, unsigned np_) {
  if (ni < 0.f) return;
  bool take;
  if (ci < 0.f) take = true;
  else {
    float a = ni * cu, bq = ci * nu;
    take = (a > bq) || (a == bq && np_ < cp);
  }
  if (take) { ci = ni; cu = nu; cp = np_; }
}

__global__ __launch_bounds__(256) void k_iou(
    const float* __restrict__ priors, const float* __restrict__ targets,
    float* __restrict__ bto, int* __restrict__ bti, int P, int G, int PT) {
  int b = blockIdx.x / PT, tile = blockIdx.x % PT;
  int tid = threadIdx.x;
  int p = tile * 256 + tid;
  int pl = p < P ? p : P - 1;

  __shared__ float tx1[128], ty1[128], tx2[128], ty2[128], ta[128];
  for (int g = tid; g < G; g += 256) {
    const float* t = targets + ((size_t)b * G + g) * 15;
    float x1 = t[0], y1 = t[1], x2 = t[2], y2 = t[3];
    tx1[g] = x1; ty1[g] = y1; tx2[g] = x2; ty2[g] = y2;
    ta[g] = (x2 - x1) * (y2 - y1);
  }
  __syncthreads();

  float4 pr = ((const float4*)priors)[pl];
  float px1 = pr.x - pr.z * 0.5f, py1 = pr.y - pr.w * 0.5f;
  float px2 = pr.x + pr.z * 0.5f, py2 = pr.y + pr.w * 0.5f;
  float pa = (px2 - px1) * (py2 - py1);

  float bi = -1.f, bu = 1.f;
  int bidx = 0;
#pragma unroll 4
  for (int g = 0; g < G; ++g) {
    float ltx = fmaxf(tx1[g], px1), lty = fmaxf(ty1[g], py1);
    float rbx = fminf(tx2[g], px2), rby = fminf(ty2[g], py2);
    float iw = fmaxf(rbx - ltx, 0.f), ih = fmaxf(rby - lty, 0.f);
    float inter = iw * ih;
    float uni = ta[g] + pa - inter;
    if (inter * bu > bi * uni) { bi = inter; bu = uni; bidx = g; }
  }
  if (p < P) {
    bto[(size_t)b * P + p] = bi / bu;
    bti[(size_t)b * P + p] = bidx;
  }
}

__global__ __launch_bounds__(256) void k_bp(
    const float* __restrict__ priors, const float* __restrict__ targets,
    unsigned long long* __restrict__ bp, int P, int G, int NGC, int PC) {
  int bc = blockIdx.x;
  int pc = bc % PC;
  int gcb = (bc / PC) % NGC;
  int b = bc / (PC * NGC);
  int g0 = gcb * GC;
  int tid = threadIdx.x;

  __shared__ float sg[GC * 5];
  if (tid < GC * 5) {
    int j = tid / 5, c = tid % 5;
    int g = g0 + j;
    float v = 0.f;
    if (g < G) {
      const float* t = targets + ((size_t)b * G + g) * 15;
      v = (c < 4) ? t[c] : (t[2] - t[0]) * (t[3] - t[1]);
    }
    sg[tid] = v;
  }
  __syncthreads();

  float gx1[GC], gy1[GC], gx2[GC], gy2[GC], ga[GC];
#pragma unroll
  for (int j = 0; j < GC; ++j) {
    gx1[j] = sg[j * 5 + 0]; gy1[j] = sg[j * 5 + 1];
    gx2[j] = sg[j * 5 + 2]; gy2[j] = sg[j * 5 + 3];
    ga[j] = sg[j * 5 + 4];
  }

  float bi[GC], bu[GC];
  unsigned bpp[GC];
#pragma unroll
  for (int j = 0; j < GC; ++j) { bi[j] = -1.f; bu[j] = 1.f; bpp[j] = 0; }

  int chunk = (P + PC - 1) / PC;
  int ps = pc * chunk;
  int pe = ps + chunk; if (pe > P) pe = P;

  for (int p = ps + tid; p < pe; p += 256) {
    float4 pr = ((const float4*)priors)[p];
    float px1 = pr.x - pr.z * 0.5f, py1 = pr.y - pr.w * 0.5f;
    float px2 = pr.x + pr.z * 0.5f, py2 = pr.y + pr.w * 0.5f;
    float pa = (px2 - px1) * (py2 - py1);
#pragma unroll
    for (int j = 0; j < GC; ++j) {
      float ltx = fmaxf(gx1[j], px1), lty = fmaxf(gy1[j], py1);
      float rbx = fminf(gx2[j], px2), rby = fminf(gy2[j], py2);
      float iw = fmaxf(rbx - ltx, 0.f), ih = fmaxf(rby - lty, 0.f);
      float inter = iw * ih;
      float uni = ga[j] + pa - inter;
      if (inter * bu[j] > bi[j] * uni) { bi[j] = inter; bu[j] = uni; bpp[j] = (unsigned)p; }
    }
  }

  __shared__ float si[GC * 256], su[GC * 256];
  __shared__ unsigned sp[GC * 256];
#pragma unroll
  for (int j = 0; j < GC; ++j) {
    si[j * 256 + tid] = bi[j]; su[j * 256 + tid] = bu[j]; sp[j * 256 + tid] = bpp[j];
  }
  __syncthreads();
  {
    int j = tid >> 5, s = tid & 31;
    float ci = -1.f, cu = 1.f; unsigned cp = 0;
    for (int t = s; t < 256; t += 32)
      combine(ci, cu, cp, si[j * 256 + t], su[j * 256 + t], sp[j * 256 + t]);
    __syncthreads();
    si[j * 256 + s] = ci; su[j * 256 + s] = cu; sp[j * 256 + s] = cp;
  }
  __syncthreads();
  if (tid < GC) {
    int j = tid;
    float ci = -1.f, cu = 1.f; unsigned cp = 0;
    for (int t = 0; t < 32; ++t)
      combine(ci, cu, cp, si[j * 256 + t], su[j * 256 + t], sp[j * 256 + t]);
    int g = g0 + j;
    if (g < G && ci >= 0.f) {
      float v = ci / cu;
      unsigned long long packed =
          ((unsigned long long)__float_as_uint(v) << 32) | (unsigned)(~cp);
      atomicMax(&bp[(size_t)b * G + g], packed);  // native u64 max, low traffic
    }
  }
}

__global__ void k_scatter(const unsigned long long* __restrict__ bp,
                          float* __restrict__ bto, int* __restrict__ bti,
                          int* __restrict__ anyv, int P, int G) {
  int b = blockIdx.x, g = threadIdx.x;
  __shared__ unsigned spp[128];
  __shared__ int s_any;
  if (g == 0) s_any = 0;
  __syncthreads();
  unsigned long long m = bp[(size_t)b * G + g];
  unsigned pp = ~(unsigned)m;
  float val = __uint_as_float((unsigned)(m >> 32));
  bool ok = (m != 0ULL);
  float oldv = 0.f;
  if (ok) oldv = bto[(size_t)b * P + pp];
  spp[g] = ok ? pp : 0xFFFFFFFFu;
  if (ok && val >= 0.2f) s_any = 1;
  __syncthreads();
  bool win = ok;
  for (int g2 = g + 1; g2 < G; ++g2)
    if (spp[g2] == pp) win = false;
  if (win) {
    bto[(size_t)b * P + pp] = (val >= 0.2f) ? 2.0f : oldv;
    bti[(size_t)b * P + pp] = g;
  }
  __syncthreads();
  if (g == 0) anyv[b] = s_any;
}

__global__ __launch_bounds__(256) void k_main(
    const float* __restrict__ loc, const float* __restrict__ conf,
    const float* __restrict__ lm, const float* __restrict__ priors,
    const float* __restrict__ targets, const float* __restrict__ bto,
    const int* __restrict__ bti, const int* __restrict__ anyv,
    float* __restrict__ mine, unsigned* __restrict__ h1,
    double* __restrict__ pll, double* __restrict__ pllm,
    double* __restrict__ plc, int* __restrict__ pnp, int P, int G, int PT) {
  int b = blockIdx.x / PT, tile = blockIdx.x % PT;
  int tid = threadIdx.x;
  int p = tile * 256 + tid;

  __shared__ float st[128 * 15];
  __shared__ unsigned hist[1024];
  __shared__ double rs[12];
  __shared__ int ri[4];

  for (int i = tid; i < G * 15; i += 256) st[i] = targets[(size_t)b * G * 15 + i];
  for (int i = tid; i < 1024; i += 256) hist[i] = 0;
  __syncthreads();

  double ll = 0, llm = 0, lc = 0;
  int np = 0;
  if (p < P) {
    size_t idx = (size_t)b * P + p;
    int av = anyv[b];
    float ov = bto[idx];
    int ti = bti[idx];
    bool pos = av && (ov >= 0.35f);

    float2 c = ((const float2*)conf)[idx];
    float mx = fmaxf(c.x, c.y);
    float lse = mx + logf(expf(c.x - mx) + expf(c.y - mx));
    float ce = lse - (pos ? c.y : c.x);
    float mv = pos ? 0.f : ce;
    mine[idx] = mv;
    atomicAdd(&hist[__float_as_uint(mv) >> 21], 1u);

    if (pos) {
      np = 1;
      lc = (double)ce;
      float4 pr = ((const float4*)priors)[p];
      const float* t = st + ti * 15;
      float dx = 0.1f * pr.z, dy = 0.1f * pr.w;
      float gx = ((t[0] + t[2]) * 0.5f - pr.x) / dx;
      float gy = ((t[1] + t[3]) * 0.5f - pr.y) / dy;
      float gw = logf((t[2] - t[0]) / pr.z) * 5.0f;
      float gh = logf((t[3] - t[1]) / pr.w) * 5.0f;
      float4 ld = ((const float4*)loc)[idx];
      ll = (double)(sl1(ld.x - gx) + sl1(ld.y - gy) + sl1(ld.z - gw) +
                    sl1(ld.w - gh));
      const float2* lmd = (const float2*)lm + idx * 5;
      float s = 0.f;
#pragma unroll
      for (int j = 0; j < 5; ++j) {
        float2 lv = lmd[j];
        float ex = (t[4 + 2 * j] - pr.x) / dx;
        float ey = (t[5 + 2 * j] - pr.y) / dy;
        s += sl1(lv.x - ex) + sl1(lv.y - ey);
      }
      llm = (double)s;
    }
  }

  ll = dwave(ll);
  llm = dwave(llm);
  lc = dwave(lc);
#pragma unroll
  for (int o = 32; o; o >>= 1) np += __shfl_down(np, o);
  int lane = tid & 63, wid = tid >> 6;
  if (lane == 0) { rs[wid] = ll; rs[4 + wid] = llm; rs[8 + wid] = lc; ri[wid] = np; }
  __syncthreads();
  if (tid == 0) {
    pll[blockIdx.x] = rs[0] + rs[1] + rs[2] + rs[3];
    pllm[blockIdx.x] = rs[4] + rs[5] + rs[6] + rs[7];
    plc[blockIdx.x] = rs[8] + rs[9] + rs[10] + rs[11];
    pnp[blockIdx.x] = ri[0] + ri[1] + ri[2] + ri[3];
  }
  for (int i = tid; i < 1024; i += 256)
    if (hist[i]) atomicAdd(&h1[(size_t)b * 1024 + i], hist[i]);
}

__global__ __launch_bounds__(256) void k_sel1(const unsigned* __restrict__ h1,
                                              const int* __restrict__ pnp,
                                              int* __restrict__ num_pos, int P,
                                              int PT, int* __restrict__ pfx1,
                                              int* __restrict__ k1) {
  int b = blockIdx.x, tid = threadIdx.x;
  // reduce per-block pos counts -> num_pos[b]
  __shared__ int sn[256];
  int n = 0;
  for (int i = tid; i < PT; i += 256) n += pnp[b * PT + i];
  sn[tid] = n;
  __syncthreads();
  for (int off = 128; off; off >>= 1) {
    if (tid < off) sn[tid] += sn[tid + off];
    __syncthreads();
  }
  int npos = sn[0];
  if (tid == 0) num_pos[b] = npos;

  const unsigned* h = h1 + (size_t)b * 1024;
  __shared__ unsigned S[256];
  unsigned p0 = h[tid * 4], p1 = h[tid * 4 + 1], p2 = h[tid * 4 + 2],
           p3 = h[tid * 4 + 3];
  S[tid] = p0 + p1 + p2 + p3;
  __syncthreads();
  for (int off = 1; off < 256; off <<= 1) {
    unsigned add = (tid + off < 256) ? S[tid + off] : 0;
    __syncthreads();
    S[tid] += add;
    __syncthreads();
  }
  long long k = 7LL * (long long)npos;
  long long cap = P - 1;
  if (k > cap) k = cap;
  int cnt = __syncthreads_count(k > 0 && (long long)S[tid] >= k);
  if (cnt == 0) {
    if (tid == 0) { pfx1[b] = -1; k1[b] = 0; }
    return;
  }
  int seg = cnt - 1;
  if (tid == seg) {
    long long cum = (seg + 1 < 256) ? (long long)S[seg + 1] : 0;
    unsigned hv[4] = {p0, p1, p2, p3};
    int bin = seg * 4;
    for (int j = 3; j >= 0; --j) {
      if (cum + hv[j] >= k) { bin = seg * 4 + j; break; }
      cum += hv[j];
    }
    pfx1[b] = bin;
    k1[b] = (int)(k - cum);
  }
}

__global__ __launch_bounds__(256) void k_h2(const float* __restrict__ mine,
                                            const int* __restrict__ pfx1,
                                            unsigned* __restrict__ h2, int P,
                                            int PT) {
  int b = blockIdx.x / PT;
  int p = (blockIdx.x % PT) * 256 + threadIdx.x;
  __shared__ unsigned hist[2048];
  for (int i = threadIdx.x; i < 2048; i += 256) hist[i] = 0;
  __syncthreads();
  int pf = pfx1[b];
  if (p < P) {
    unsigned bits = __float_as_uint(mine[(size_t)b * P + p]);
    if ((int)(bits >> 21) == pf) atomicAdd(&hist[(bits >> 10) & 2047], 1u);
  }
  __syncthreads();
  for (int i = threadIdx.x; i < 2048; i += 256)
    if (hist[i]) atomicAdd(&h2[(size_t)b * 2048 + i], hist[i]);
}

__global__ __launch_bounds__(256) void k_sel2(const unsigned* __restrict__ h2,
                                              const int* __restrict__ pfx1,
                                              const int* __restrict__ k1,
                                              int* __restrict__ pfx21,
                                              int* __restrict__ k2) {
  int b = blockIdx.x, tid = threadIdx.x;
  const unsigned* h = h2 + (size_t)b * 2048;
  __shared__ unsigned S[256];
  unsigned hv[8];
  unsigned s = 0;
#pragma unroll
  for (int j = 0; j < 8; ++j) { hv[j] = h[tid * 8 + j]; s += hv[j]; }
  S[tid] = s;
  __syncthreads();
  for (int off = 1; off < 256; off <<= 1) {
    unsigned add = (tid + off < 256) ? S[tid + off] : 0;
    __syncthreads();
    S[tid] += add;
    __syncthreads();
  }
  int pf = pfx1[b];
  long long k = (long long)k1[b];
  int cnt = __syncthreads_count(pf >= 0 && (long long)S[tid] >= k);
  if (cnt == 0) {
    if (tid == 0) { pfx21[b] = -1; k2[b] = 0; }
    return;
  }
  int seg = cnt - 1;
  if (tid == seg) {
    long long cum = (seg + 1 < 256) ? (long long)S[seg + 1] : 0;
    int bin = seg * 8;
    for (int j = 7; j >= 0; --j) {
      if (cum + hv[j] >= k) { bin = seg * 8 + j; break; }
      cum += hv[j];
    }
    pfx21[b] = (pf << 11) | bin;
    k2[b] = (int)(k - cum);
  }
}

__global__ __launch_bounds__(256) void k_h3(const float* __restrict__ mine,
                                            const int* __restrict__ pfx21,
                                            unsigned* __restrict__ h3, int P,
                                            int PT) {
  int b = blockIdx.x / PT;
  int p = (blockIdx.x % PT) * 256 + threadIdx.x;
  __shared__ unsigned hist[1024];
  for (int i = threadIdx.x; i < 1024; i += 256) hist[i] = 0;
  __syncthreads();
  int pf = pfx21[b];
  if (p < P) {
    unsigned bits = __float_as_uint(mine[(size_t)b * P + p]);
    if ((int)(bits >> 10) == pf) atomicAdd(&hist[bits & 1023], 1u);
  }
  __syncthreads();
  for (int i = threadIdx.x; i < 1024; i += 256)
    if (hist[i]) atomicAdd(&h3[(size_t)b * 1024 + i], hist[i]);
}

__global__ __launch_bounds__(256) void k_sel3(const unsigned* __restrict__ h3,
                                              const int* __restrict__ pfx21,
                                              const int* __restrict__ k2,
                                              int* __restrict__ tbits,
                                              double* __restrict__ tieadd) {
  int b = blockIdx.x, tid = threadIdx.x;
  const unsigned* h = h3 + (size_t)b * 1024;
  __shared__ unsigned S[256];
  unsigned p0 = h[tid * 4], p1 = h[tid * 4 + 1], p2 = h[tid * 4 + 2],
           p3 = h[tid * 4 + 3];
  S[tid] = p0 + p1 + p2 + p3;
  __syncthreads();
  for (int off = 1; off < 256; off <<= 1) {
    unsigned add = (tid + off < 256) ? S[tid + off] : 0;
    __syncthreads();
    S[tid] += add;
    __syncthreads();
  }
  int pf = pfx21[b];
  long long k = (long long)k2[b];
  int cnt = __syncthreads_count(pf >= 0 && (long long)S[tid] >= k);
  if (cnt == 0) {
    if (tid == 0) tbits[b] = -1;  // tieadd[b] stays 0 (memset)
    return;
  }
  int seg = cnt - 1;
  if (tid == seg) {
    long long cum = (seg + 1 < 256) ? (long long)S[seg + 1] : 0;
    unsigned hv[4] = {p0, p1, p2, p3};
    int bin = seg * 4;
    for (int j = 3; j >= 0; --j) {
      if (cum + hv[j] >= k) { bin = seg * 4 + j; break; }
      cum += hv[j];
    }
    unsigned tb = ((unsigned)pf << 10) | (unsigned)bin;
    tbits[b] = (int)tb;
    long long nat = k - cum;
    tieadd[b] = (double)nat * (double)__uint_as_float(tb);
  }
}

__global__ __launch_bounds__(256) void k_fsum(const float* __restrict__ mine,
                                              const int* __restrict__ tbits,
                                              double* __restrict__ pfs, int P,
                                              int PT) {
  int b = blockIdx.x / PT;
  int p = (blockIdx.x % PT) * 256 + threadIdx.x;
  unsigned tb = (unsigned)tbits[b];
  double v = 0.0;
  if (p < P) {
    unsigned bits = __float_as_uint(mine[(size_t)b * P + p]);
    if (bits > tb) v = (double)__uint_as_float(bits);
  }
  v = dwave(v);
  __shared__ double rs[4];
  int lane = threadIdx.x & 63, wid = threadIdx.x >> 6;
  if (lane == 0) rs[wid] = v;
  __syncthreads();
  if (threadIdx.x == 0) pfs[blockIdx.x] = rs[0] + rs[1] + rs[2] + rs[3];
}

__global__ __launch_bounds__(256) void k_fin(
    const double* __restrict__ pll, const double* __restrict__ pllm,
    const double* __restrict__ plc, const double* __restrict__ pfs,
    const double* __restrict__ tieadd, const int* __restrict__ num_pos,
    float* __restrict__ out, int NB, int B) {
  int tid = threadIdx.x;
  double a = 0, c = 0, d = 0, f = 0, t = 0, n = 0;
  for (int i = tid; i < NB; i += 256) {
    a += pll[i]; c += pllm[i]; d += plc[i]; f += pfs[i];
  }
  for (int i = tid; i < B; i += 256) { t += tieadd[i]; n += (double)num_pos[i]; }
  a = dwave(a); c = dwave(c); d = dwave(d); f = dwave(f); t = dwave(t);
  n = dwave(n);
  __shared__ double rs[6 * 4];
  int lane = tid & 63, wid = tid >> 6;
  if (lane == 0) {
    rs[wid] = a; rs[4 + wid] = c; rs[8 + wid] = d;
    rs[12 + wid] = f; rs[16 + wid] = t; rs[20 + wid] = n;
  }
  __syncthreads();
  if (tid == 0) {
    double A = rs[0] + rs[1] + rs[2] + rs[3];
    double C = rs[4] + rs[5] + rs[6] + rs[7];
    double D = rs[8] + rs[9] + rs[10] + rs[11];
    double F = rs[12] + rs[13] + rs[14] + rs[15];
    double T = rs[16] + rs[17] + rs[18] + rs[19];
    double N = rs[20] + rs[21] + rs[22] + rs[23];
    if (N < 1.0) N = 1.0;
    out[0] = (float)(A / N);            // loss_l / N
    out[1] = (float)((D + F + T) / N);  // loss_c / N
    out[2] = (float)(C / N);            // loss_landm / N1 (== N)
  }
}

extern "C" void kernel_launch(void* const* d_in, const int* in_sizes, int n_in,
                              void* d_out, int out_size, void* d_ws,
                              size_t ws_size, hipStream_t stream) {
  const float* loc = (const float*)d_in[0];
  const float* conf = (const float*)d_in[1];
  const float* lm = (const float*)d_in[2];
  const float* priors = (const float*)d_in[3];
  const float* targets = (const float*)d_in[4];

  int P = in_sizes[3] / 4;
  int B = in_sizes[0] / (4 * P);
  int G = in_sizes[4] / (15 * B);
  int PT = (P + 255) / 256;
  int NB = B * PT;
  int NGC = (G + GC - 1) / GC;
  int PC = 4;

  char* w = (char*)d_ws;
  size_t off = 0;
  // ---- zeroed region ----
  unsigned long long* bp = (unsigned long long*)(w + off);
  off += (size_t)B * G * 8;
  double* tieadd = (double*)(w + off);
  off += (size_t)B * 8;
  int* ctrl = (int*)(w + off);
  off += (size_t)(8 * B) * 4;
  int* anyv = ctrl;
  int* num_pos = ctrl + B;
  int* pfx1 = ctrl + 2 * B;
  int* k1 = ctrl + 3 * B;
  int* pfx21 = ctrl + 4 * B;
  int* k2 = ctrl + 5 * B;
  int* tbits = ctrl + 6 * B;
  unsigned* h1 = (unsigned*)(w + off);
  off += (size_t)B * 1024 * 4;
  unsigned* h2 = (unsigned*)(w + off);
  off += (size_t)B * 2048 * 4;
  unsigned* h3 = (unsigned*)(w + off);
  off += (size_t)B * 1024 * 4;
  size_t clear_bytes = off;
  // ---- non-zeroed region (written unconditionally) ----
  off = (off + 255) & ~(size_t)255;
  float* bto = (float*)(w + off);
  off += (size_t)B * P * 4;
  int* bti = (int*)(w + off);
  off += (size_t)B * P * 4;
  float* mine = (float*)(w + off);
  off += (size_t)B * P * 4;
  double* pll = (double*)(w + off);
  off += (size_t)NB * 8;
  double* pllm = (double*)(w + off);
  off += (size_t)NB * 8;
  double* plc = (double*)(w + off);
  off += (size_t)NB * 8;
  double* pfs = (double*)(w + off);
  off += (size_t)NB * 8;
  int* pnp = (int*)(w + off);
  off += (size_t)NB * 4;

  hipMemsetAsync(d_ws, 0, clear_bytes, stream);

  k_iou<<<B * PT, 256, 0, stream>>>(priors, targets, bto, bti, P, G, PT);
  k_bp<<<B * NGC * PC, 256, 0, stream>>>(priors, targets, bp, P, G, NGC, PC);
  k_scatter<<<B, G, 0, stream>>>(bp, bto, bti, anyv, P, G);
  k_main<<<B * PT, 256, 0, stream>>>(loc, conf, lm, priors, targets, bto, bti,
                                     anyv, mine, h1, pll, pllm, plc, pnp, P, G,
                                     PT);
  k_sel1<<<B, 256, 0, stream>>>(h1, pnp, num_pos, P, PT, pfx1, k1);
  k_h2<<<B * PT, 256, 0, stream>>>(mine, pfx1, h2, P, PT);
  k_sel2<<<B, 256, 0, stream>>>(h2, pfx1, k1, pfx21, k2);
  k_h3<<<B * PT, 256, 0, stream>>>(mine, pfx21, h3, P, PT);
  k_sel3<<<B, 256, 0, stream>>>(h3, pfx21, k2, tbits, tieadd);
  k_fsum<<<B * PT, 256, 0, stream>>>(mine, tbits, pfs, P, PT);
  k_fin<<<1, 256, 0, stream>>>(pll, pllm, plc, pfs, tieadd, num_pos,
                               (float*)d_out, NB, B);
}